// Round 9
// baseline (150.021 us; speedup 1.0000x reference)
//
#include <hip/hip_runtime.h>
#include <hip/hip_bf16.h>

// ENN — R14: 2 launches, both cheap.
// k_main (grid 2048 = atom i x half, R7's proven geometry): R13's self-contained
//   prologue (LM staged to LDS; T2 = c*(LM@W1j+be1) from coalesced independent
//   We1 column loads; per-block We2 hi/lo B-frags), R5/R10 verified main loop with
//   LDS T2 gather. NO atomics/election: plain-store partial to Vhalf[bid] (unique
//   slot, no init needed) and (half==0) the diagonal-z row to diagz[i] (from LDS).
// k_post (grid 256, 4 atoms/block, R7-verified): Rall = Vhalf[2i]+Vhalf[2i+1],
//   dgt from diagz, S_ii matvec, V, newH, out atomicAdd.
// Rationale: fixed overhead measured ~65us for 1-2 launches (3rd launch +20);
// in-main election epilogue costs ~10us (R10 vs R7); kernel time is the lever.

#define N_ATOMS 1024
#define L_DIM 64
#define CSCALE 2.8853900817779268f   // 2*log2(e)
#define T2LD 68                      // padded T2 row stride (floats)

typedef _Float16 f16x8 __attribute__((ext_vector_type(8)));
typedef __fp16  fp16x2 __attribute__((ext_vector_type(2)));
typedef float f32x4 __attribute__((ext_vector_type(4)));

__device__ __forceinline__ float tanh_fast(float x) {
    float e = __builtin_amdgcn_exp2f(x * CSCALE);
    float r = __builtin_amdgcn_rcpf(e + 1.0f);
    return fmaf(-2.0f, r, 1.0f);
}

// ---------------- Stage 1: main (grid 2048: i = bid>>1, half = bid&1) ----------------
__global__ __launch_bounds__(256) void k_main(const int* __restrict__ cat,
                                              const float* __restrict__ Z,
                                              const float* __restrict__ LM,
                                              const float* __restrict__ We1,
                                              const float* __restrict__ be1,
                                              const float* __restrict__ We2,
                                              const float* __restrict__ be2,
                                              float* __restrict__ Vhalf,
                                              float* __restrict__ diagz) {
    int bid = blockIdx.x;
    int i = bid >> 1, half = bid & 1;
    int t = threadIdx.x;
    int lane = t & 63;
    int wave = t >> 6;          // 0..3
    int nlo = lane & 15;
    int quad = lane >> 4;

    __shared__ __align__(16) float d2s[512];            // 2 KB
    __shared__ int   cats[512];                         // 2 KB
    __shared__ __align__(16) float LMs[20 * L_DIM];     // 5 KB
    __shared__ __align__(16) float T2s[20 * T2LD];      // 5.4 KB
    __shared__ __align__(16) float preIs[L_DIM];
    __shared__ float red[256];
    __shared__ f16x8 bLs[8 * 64];                       // 8 KB

    // ---- stage: cats/d2 for this half, LM table ----
    float zi0 = Z[i * 3], zi1 = Z[i * 3 + 1], zi2 = Z[i * 3 + 2];
    for (int p = t; p < 512; p += 256) {
        int j = half * 512 + p;
        cats[p] = cat[j];
        float a = zi0 - Z[j * 3], b = zi1 - Z[j * 3 + 1], c = zi2 - Z[j * 3 + 2];
        d2s[p] = a * a + b * b + c * c;
    }
    for (int p = t; p < 20 * L_DIM; p += 256) LMs[p] = LM[p];
    int ci = cat[i];
    __syncthreads();

    // ---- T2 build: rows c = wave+4r, col = lane; one We1 column load per m ----
    {
        float a0 = 0.f, a1 = 0.f, a2 = 0.f, a3 = 0.f, a4 = 0.f;
#pragma unroll 16
        for (int m = 0; m < L_DIM; m++) {
            float w = We1[(L_DIM + m) * L_DIM + lane];
            a0 = fmaf(LMs[(wave +  0) * L_DIM + m], w, a0);
            a1 = fmaf(LMs[(wave +  4) * L_DIM + m], w, a1);
            a2 = fmaf(LMs[(wave +  8) * L_DIM + m], w, a2);
            a3 = fmaf(LMs[(wave + 12) * L_DIM + m], w, a3);
            a4 = fmaf(LMs[(wave + 16) * L_DIM + m], w, a4);
        }
        float b = be1[lane];
        T2s[(wave +  0) * T2LD + lane] = (a0 + b) * CSCALE;
        T2s[(wave +  4) * T2LD + lane] = (a1 + b) * CSCALE;
        T2s[(wave +  8) * T2LD + lane] = (a2 + b) * CSCALE;
        T2s[(wave + 12) * T2LD + lane] = (a3 + b) * CSCALE;
        T2s[(wave + 16) * T2LD + lane] = (a4 + b) * CSCALE;
    }
    if (wave == 0) {
        float s = 0.f;
#pragma unroll 16
        for (int m = 0; m < L_DIM; m++)
            s = fmaf(LMs[ci * L_DIM + m], We1[m * L_DIM + lane], s);
        preIs[lane] = s * CSCALE;
    }

    // ---- B fragments (verified R5 prologue): hi regs / lo LDS ----
    f16x8 bH[4][2];
    float biasR[4];
#pragma unroll
    for (int nt = 0; nt < 4; nt++) {
        float psum = 0.f;
#pragma unroll
        for (int kt = 0; kt < 2; kt++) {
            f16x8 hi8, lo8;
#pragma unroll
            for (int e = 0; e < 8; e++) {
                float x = We2[(kt * 32 + quad * 8 + e) * L_DIM + nt * 16 + nlo];
                psum += x;
                float wp = -2.0f * CSCALE * x;
                _Float16 hi = (_Float16)wp;
                hi8[e] = hi;
                lo8[e] = (_Float16)(wp - (float)hi);
            }
            bH[nt][kt] = hi8;
            if (wave == 0) bLs[(kt * 4 + nt) * 64 + lane] = lo8;
        }
        psum += __shfl_xor(psum, 16);
        psum += __shfl_xor(psum, 32);
        biasR[nt] = CSCALE * (be2[nt * 16 + nlo] + psum);
    }

    // per-lane m-block bases + wz
    int mbs[4];
    f32x4 wzR[4];
#pragma unroll
    for (int g = 0; g < 4; g++) {
        int mb = ((g >> 1) << 5) + (quad << 3) + ((g & 1) << 2);
        mbs[g] = mb;
        f32x4 wz = *(const f32x4*)(We1 + 2 * L_DIM * L_DIM + mb);
        wzR[g] = wz * CSCALE;
    }

    __syncthreads();   // T2s, preIs, bLs ready

    f32x4 aiR[4];
#pragma unroll
    for (int g = 0; g < 4; g++) aiR[g] = *(const f32x4*)(preIs + mbs[g]);

    // gather for k=0 (aiR folded)
    int sc0 = cats[nlo + wave * 128];   // (wave*8+0)*16 + nlo
    const float* Tr0 = T2s + sc0 * T2LD;
    f32x4 p0 = *(const f32x4*)(Tr0 + mbs[0]) + aiR[0];
    f32x4 p1 = *(const f32x4*)(Tr0 + mbs[1]) + aiR[1];
    f32x4 p2 = *(const f32x4*)(Tr0 + mbs[2]) + aiR[2];
    f32x4 p3 = *(const f32x4*)(Tr0 + mbs[3]) + aiR[3];

    f32x4 Vr4 = {0.f, 0.f, 0.f, 0.f};
    for (int k = 0; k < 8; k++) {
        float d2 = d2s[(wave * 8 + k) * 16 + nlo];
        f32x4 d2v = {d2, d2, d2, d2};

        f32x4 z0 = p0 + d2v * wzR[0];
        f32x4 z1 = p1 + d2v * wzR[1];
        f32x4 z2 = p2 + d2v * wzR[2];
        f32x4 z3 = p3 + d2v * wzR[3];
        f32x4 ex0, ex1, ex2, ex3;
#pragma unroll
        for (int e = 0; e < 4; e++) {
            ex0[e] = __builtin_amdgcn_exp2f(z0[e]);
            ex1[e] = __builtin_amdgcn_exp2f(z1[e]);
            ex2[e] = __builtin_amdgcn_exp2f(z2[e]);
            ex3[e] = __builtin_amdgcn_exp2f(z3[e]);
        }
        ex0 += 1.0f; ex1 += 1.0f; ex2 += 1.0f; ex3 += 1.0f;
        f32x4 r0, r1, r2, r3;
#pragma unroll
        for (int e = 0; e < 4; e++) {
            r0[e] = __builtin_amdgcn_rcpf(ex0[e]);
            r1[e] = __builtin_amdgcn_rcpf(ex1[e]);
            r2[e] = __builtin_amdgcn_rcpf(ex2[e]);
            r3[e] = __builtin_amdgcn_rcpf(ex3[e]);
        }
        union { f16x8 v; fp16x2 h2[4]; } u0, u1;
        u0.h2[0] = __builtin_amdgcn_cvt_pkrtz(r0[0], r0[1]);
        u0.h2[1] = __builtin_amdgcn_cvt_pkrtz(r0[2], r0[3]);
        u0.h2[2] = __builtin_amdgcn_cvt_pkrtz(r1[0], r1[1]);
        u0.h2[3] = __builtin_amdgcn_cvt_pkrtz(r1[2], r1[3]);
        u1.h2[0] = __builtin_amdgcn_cvt_pkrtz(r2[0], r2[1]);
        u1.h2[1] = __builtin_amdgcn_cvt_pkrtz(r2[2], r2[3]);
        u1.h2[2] = __builtin_amdgcn_cvt_pkrtz(r3[0], r3[1]);
        u1.h2[3] = __builtin_amdgcn_cvt_pkrtz(r3[2], r3[3]);
        f16x8 aH0 = u0.v, aH1 = u1.v;

        if (k < 7) {
            int sc = cats[(wave * 8 + k + 1) * 16 + nlo];
            const float* Tr = T2s + sc * T2LD;
            p0 = *(const f32x4*)(Tr + mbs[0]) + aiR[0];
            p1 = *(const f32x4*)(Tr + mbs[1]) + aiR[1];
            p2 = *(const f32x4*)(Tr + mbs[2]) + aiR[2];
            p3 = *(const f32x4*)(Tr + mbs[3]) + aiR[3];
        }

#pragma unroll
        for (int nt = 0; nt < 4; nt++) {
            f16x8 bl0 = bLs[(0 * 4 + nt) * 64 + lane];
            f16x8 bl1 = bLs[(1 * 4 + nt) * 64 + lane];
            f32x4 acc = {biasR[nt], biasR[nt], biasR[nt], biasR[nt]};
            acc = __builtin_amdgcn_mfma_f32_16x16x32_f16(aH0, bH[nt][0], acc, 0, 0, 0);
            acc = __builtin_amdgcn_mfma_f32_16x16x32_f16(aH0, bl0, acc, 0, 0, 0);
            acc = __builtin_amdgcn_mfma_f32_16x16x32_f16(aH1, bH[nt][1], acc, 0, 0, 0);
            acc = __builtin_amdgcn_mfma_f32_16x16x32_f16(aH1, bl1, acc, 0, 0, 0);
            f32x4 ev;
#pragma unroll
            for (int r4 = 0; r4 < 4; r4++) ev[r4] = __builtin_amdgcn_exp2f(acc[r4]);
            ev += 1.0f;
            f32x4 rv;
#pragma unroll
            for (int r4 = 0; r4 < 4; r4++) rv[r4] = __builtin_amdgcn_rcpf(ev[r4]);
            Vr4 += rv;
        }
    }

    red[t] = Vr4[0] + Vr4[1] + Vr4[2] + Vr4[3];
    __syncthreads();

    if (t < 64) {
        float r = red[t] + red[t + 64] + red[t + 128] + red[t + 192];
#pragma unroll
        for (int o = 32; o > 0; o >>= 1) r += __shfl_xor(r, o);
        // half-0 block also exports the diagonal z row (LDS-resident terms)
        if (half == 0) diagz[i * L_DIM + t] = preIs[t] + T2s[ci * T2LD + t];
        if (t == 0) Vhalf[bid] = r;
    }
}

// ---------------- Stage 2: diagonal + epilogue (4 atoms/block, R7-verified) ----------------
__global__ __launch_bounds__(256) void k_post(const int* __restrict__ cat,
                                              const float* __restrict__ LM,
                                              const float* __restrict__ We2,
                                              const float* __restrict__ be2,
                                              const float* __restrict__ Wh1,
                                              const float* __restrict__ bh1,
                                              const float* __restrict__ Wh2,
                                              const float* __restrict__ bh2,
                                              const float* __restrict__ Wo,
                                              const float* __restrict__ bo,
                                              const float* __restrict__ Vhalf,
                                              const float* __restrict__ diagz,
                                              float* __restrict__ out) {
    int t = threadIdx.x;
    int sub = t >> 6, lane = t & 63;
    int i = blockIdx.x * 4 + sub;
    __shared__ float dgt[4][L_DIM];
    __shared__ float hrow_s[4][L_DIM];
    __shared__ float hh_s[4][L_DIM];

    float Rall = Vhalf[2 * i] + Vhalf[2 * i + 1];
    float z = diagz[i * L_DIM + lane];
    float rr = __builtin_amdgcn_rcpf(__builtin_amdgcn_exp2f(z) + 1.0f);
    dgt[sub][lane] = fmaf(-2.0f, rr, 1.0f);
    hrow_s[sub][lane] = LM[cat[i] * L_DIM + lane];
    __syncthreads();

    float S = be2[lane];
#pragma unroll
    for (int m = 0; m < L_DIM; m++) S = fmaf(dgt[sub][m], We2[m * L_DIM + lane], S);
    float rd = __builtin_amdgcn_rcpf(__builtin_amdgcn_exp2f(S * CSCALE) + 1.0f);
#pragma unroll
    for (int o = 32; o > 0; o >>= 1) rd += __shfl_xor(rd, o);
    float V = fmaf(-2.0f, Rall - rd, (float)(1023 * L_DIM));
    float s = 0.f;
#pragma unroll
    for (int m = 0; m < L_DIM; m++) s = fmaf(hrow_s[sub][m], Wh1[m * L_DIM + lane], s);
    s = fmaf(V, Wh1[L_DIM * L_DIM + lane], s) + bh1[lane];
    hh_s[sub][lane] = tanh_fast(s);
    __syncthreads();

    float s2 = 0.f;
#pragma unroll
    for (int m = 0; m < L_DIM; m++) s2 = fmaf(hh_s[sub][m], Wh2[m * L_DIM + lane], s2);
    float nh = tanh_fast(s2 + bh2[lane]);
    float w = nh * Wo[lane];
#pragma unroll
    for (int o = 32; o > 0; o >>= 1) w += __shfl_down(w, o);
    if (lane == 0) atomicAdd(out, w + (i == 0 ? bo[0] : 0.f));
}

extern "C" void kernel_launch(void* const* d_in, const int* in_sizes, int n_in,
                              void* d_out, int out_size, void* d_ws, size_t ws_size,
                              hipStream_t stream) {
    const int*   cat = (const int*)  d_in[0];
    const float* Z   = (const float*)d_in[1];
    const float* LM  = (const float*)d_in[2];
    const float* We1 = (const float*)d_in[3];
    const float* be1 = (const float*)d_in[4];
    const float* We2 = (const float*)d_in[5];
    const float* be2 = (const float*)d_in[6];
    const float* Wh1 = (const float*)d_in[7];
    const float* bh1 = (const float*)d_in[8];
    const float* Wh2 = (const float*)d_in[9];
    const float* bh2 = (const float*)d_in[10];
    const float* Wo  = (const float*)d_in[11];
    const float* bo  = (const float*)d_in[12];
    float* out = (float*)d_out;

    float* ws    = (float*)d_ws;
    float* diagz = ws;                        // 1024*64
    float* Vhalf = diagz + N_ATOMS * L_DIM;   // 2048
    // Both are fully written each iteration before being read; no init needed.
    // out is memset by the harness (established R12/R13).

    k_main<<<N_ATOMS * 2, 256, 0, stream>>>(cat, Z, LM, We1, be1, We2, be2,
                                            Vhalf, diagz);
    k_post<<<N_ATOMS / 4, 256, 0, stream>>>(cat, LM, We2, be2,
                                            Wh1, bh1, Wh2, bh2, Wo, bo,
                                            Vhalf, diagz, out);
}

// Round 10
// 128.291 us; speedup vs baseline: 1.1694x; 1.1694x over previous
//
#include <hip/hip_runtime.h>
#include <hip/hip_bf16.h>

// ENN — R15: R10 skeleton (2 launches, proven) with the two measured costs fixed:
//  (a) slim election epilogue: waves 1-3 exit after red[]+barrier; wave 0 does
//      atomicAdd-return election + wave-local epilogue (dgt/hrow/hh in reused red[],
//      no barriers), fed by k_prep-precomputed diagz. R10 paid +10.5us vs bare R7.
//  (b) bH moved to LDS (bHs) to cut ~32 VGPRs (target <=64: occupancy step, m69).
// k_prep: P3/preI/diagz + bHg/bLg/biasg tables + Vpart zero.
// k_main (grid 2048 = i x half): R7-verified 8-chunk loop, all B-frags from LDS.

#define N_ATOMS 1024
#define L_DIM 64
#define CSCALE 2.8853900817779268f   // 2*log2(e)

typedef _Float16 f16x8 __attribute__((ext_vector_type(8)));
typedef __fp16  fp16x2 __attribute__((ext_vector_type(2)));
typedef float f32x4 __attribute__((ext_vector_type(4)));

__device__ __forceinline__ float tanh_fast(float x) {
    float e = __builtin_amdgcn_exp2f(x * CSCALE);
    float r = __builtin_amdgcn_rcpf(e + 1.0f);
    return fmaf(-2.0f, r, 1.0f);
}

// ---------------- Stage 1: prep ----------------
__global__ __launch_bounds__(256) void k_prep(const int* __restrict__ cat,
                                              const float* __restrict__ LM,
                                              const float* __restrict__ We1,
                                              const float* __restrict__ be1,
                                              const float* __restrict__ We2,
                                              const float* __restrict__ be2,
                                              float* __restrict__ preI,
                                              float* __restrict__ P3,
                                              float* __restrict__ diagz,
                                              float* __restrict__ Vpart,
                                              f16x8* __restrict__ bHg,
                                              f16x8* __restrict__ bLg,
                                              float* __restrict__ biasg) {
    int t = threadIdx.x;
    int sub = t >> 6, l = t & 63;
    int i = blockIdx.x * 4 + sub;
    if (t < 4) Vpart[blockIdx.x * 4 + t] = 0.f;
    __shared__ float hrow[4][L_DIM];
    hrow[sub][l] = LM[cat[i] * L_DIM + l];
    __syncthreads();
    float s1 = 0.f, s2 = 0.f;
#pragma unroll
    for (int m = 0; m < L_DIM; m++) {
        float h = hrow[sub][m];
        s1 = fmaf(h, We1[m * L_DIM + l], s1);
        s2 = fmaf(h, We1[(L_DIM + m) * L_DIM + l], s2);
    }
    float pre_i = s1 * CSCALE;
    float prejb = (s2 + be1[l]) * CSCALE;
    preI[i * L_DIM + l] = pre_i;
    diagz[i * L_DIM + l] = pre_i + prejb;
    // pack c*(prejb) into A-fragment order (verified R2/R4):
    int cc = i >> 4;
    int Ll = i & 15;
    int quad = (l >> 3) & 3;
    int L = quad * 16 + Ll;
    int g = ((l >> 5) << 1) | ((l >> 2) & 1);
    int e2 = l & 3;
    P3[cc * 1024 + g * 256 + L * 4 + e2] = prejb;

    // --- i-independent B-fragment + bias build (once, block 0; wave w <-> nt) ---
    if (blockIdx.x == 0) {
        int nt = t >> 6;          // 0..3
        int lane = t & 63;
        int q2 = lane >> 4, nl2 = lane & 15;
        float psum = 0.f;
#pragma unroll
        for (int kt = 0; kt < 2; kt++) {
            f16x8 hi8, lo8;
#pragma unroll
            for (int e = 0; e < 8; e++) {
                float x = We2[(kt * 32 + q2 * 8 + e) * L_DIM + nt * 16 + nl2];
                psum += x;
                float wp = -2.0f * CSCALE * x;
                _Float16 hi = (_Float16)wp;
                hi8[e] = hi;
                lo8[e] = (_Float16)(wp - (float)hi);
            }
            bHg[(kt * 4 + nt) * 64 + lane] = hi8;
            bLg[(kt * 4 + nt) * 64 + lane] = lo8;
        }
        psum += __shfl_xor(psum, 16);
        psum += __shfl_xor(psum, 32);
        biasg[lane * 4 + nt] = CSCALE * (be2[nt * 16 + nl2] + psum);
    }
}

// ---------------- Stage 2: fused main (grid 2048: i = bid>>1, half = bid&1) ----------------
__global__ __launch_bounds__(256) void k_main(const int* __restrict__ cat,
                                              const float* __restrict__ Z,
                                              const float* __restrict__ LM,
                                              const float* __restrict__ We1,
                                              const float* __restrict__ preI,
                                              const float* __restrict__ P3,
                                              const float* __restrict__ diagz,
                                              const f16x8* __restrict__ bHg,
                                              const f16x8* __restrict__ bLg,
                                              const float* __restrict__ biasg,
                                              const float* __restrict__ We2,
                                              const float* __restrict__ be2,
                                              const float* __restrict__ Wh1,
                                              const float* __restrict__ bh1,
                                              const float* __restrict__ Wh2,
                                              const float* __restrict__ bh2,
                                              const float* __restrict__ Wo,
                                              const float* __restrict__ bo,
                                              float* __restrict__ Vpart,
                                              float* __restrict__ out) {
    int bid = blockIdx.x;
    int i = bid >> 1, half = bid & 1;
    int t = threadIdx.x;
    int lane = t & 63;
    int wave = t >> 6;          // 0..3
    int nlo = lane & 15;
    int quad = lane >> 4;

    __shared__ float d2s[512];
    __shared__ float red[256];
    __shared__ f16x8 bHs[8 * 64];   // 8 KB (hi frags — was 32 VGPRs)
    __shared__ f16x8 bLs[8 * 64];   // 8 KB (lo frags)

    // d2 table for this i, this half of j
    float zi0 = Z[i * 3], zi1 = Z[i * 3 + 1], zi2 = Z[i * 3 + 2];
    for (int p = t; p < 512; p += 256) {
        int j = half * 512 + p;
        float a = zi0 - Z[j * 3], b = zi1 - Z[j * 3 + 1], c = zi2 - Z[j * 3 + 2];
        d2s[p] = a * a + b * b + c * c;
    }

    // per-lane constants
    f32x4 aiR[4], wzR[4];
#pragma unroll
    for (int g = 0; g < 4; g++) {
        int mb = ((g >> 1) << 5) + (quad << 3) + ((g & 1) << 2);
        aiR[g] = *(const f32x4*)(preI + i * L_DIM + mb);
        f32x4 wz = *(const f32x4*)(We1 + 2 * L_DIM * L_DIM + mb);
        wzR[g] = wz * CSCALE;
    }

    // B fragments hi+lo to LDS (cooperative: each wave stages 2 hi + 2 lo rows)
#pragma unroll
    for (int idx = 0; idx < 2; idx++) {
        int e = wave + idx * 4;
        bHs[e * 64 + lane] = bHg[e * 64 + lane];
        bLs[e * 64 + lane] = bLg[e * 64 + lane];
    }
    f32x4 bias4 = *(const f32x4*)(biasg + lane * 4);

    // 8 chunks of 16 j per wave; aiR folded into the p registers.
    const float* Pbase = P3 + (half * 32 + wave * 8) * 1024 + lane * 4;
    f32x4 p0 = *(const f32x4*)(Pbase + 0 * 256) + aiR[0];
    f32x4 p1 = *(const f32x4*)(Pbase + 1 * 256) + aiR[1];
    f32x4 p2 = *(const f32x4*)(Pbase + 2 * 256) + aiR[2];
    f32x4 p3 = *(const f32x4*)(Pbase + 3 * 256) + aiR[3];

    __syncthreads();

    f32x4 Vr4 = {0.f, 0.f, 0.f, 0.f};   // sum over this half's j,l of 1/(exp2(S')+1)
    for (int k = 0; k < 8; k++) {
        float d2 = d2s[(wave * 8 + k) * 16 + nlo];
        f32x4 d2v = {d2, d2, d2, d2};

        // A-frag: r = 1/(exp2(z)+1) per element
        f32x4 z0 = p0 + d2v * wzR[0];
        f32x4 z1 = p1 + d2v * wzR[1];
        f32x4 z2 = p2 + d2v * wzR[2];
        f32x4 z3 = p3 + d2v * wzR[3];
        f32x4 ex0, ex1, ex2, ex3;
#pragma unroll
        for (int e = 0; e < 4; e++) {
            ex0[e] = __builtin_amdgcn_exp2f(z0[e]);
            ex1[e] = __builtin_amdgcn_exp2f(z1[e]);
            ex2[e] = __builtin_amdgcn_exp2f(z2[e]);
            ex3[e] = __builtin_amdgcn_exp2f(z3[e]);
        }
        ex0 += 1.0f; ex1 += 1.0f; ex2 += 1.0f; ex3 += 1.0f;
        f32x4 r0, r1, r2, r3;
#pragma unroll
        for (int e = 0; e < 4; e++) {
            r0[e] = __builtin_amdgcn_rcpf(ex0[e]);
            r1[e] = __builtin_amdgcn_rcpf(ex1[e]);
            r2[e] = __builtin_amdgcn_rcpf(ex2[e]);
            r3[e] = __builtin_amdgcn_rcpf(ex3[e]);
        }
        union { f16x8 v; fp16x2 h2[4]; } u0, u1;
        u0.h2[0] = __builtin_amdgcn_cvt_pkrtz(r0[0], r0[1]);
        u0.h2[1] = __builtin_amdgcn_cvt_pkrtz(r0[2], r0[3]);
        u0.h2[2] = __builtin_amdgcn_cvt_pkrtz(r1[0], r1[1]);
        u0.h2[3] = __builtin_amdgcn_cvt_pkrtz(r1[2], r1[3]);
        u1.h2[0] = __builtin_amdgcn_cvt_pkrtz(r2[0], r2[1]);
        u1.h2[1] = __builtin_amdgcn_cvt_pkrtz(r2[2], r2[3]);
        u1.h2[2] = __builtin_amdgcn_cvt_pkrtz(r3[0], r3[1]);
        u1.h2[3] = __builtin_amdgcn_cvt_pkrtz(r3[2], r3[3]);
        f16x8 aH0 = u0.v, aH1 = u1.v;

        if (k < 7) {
            const float* nb = Pbase + (k + 1) * 1024;
            p0 = *(const f32x4*)(nb + 0 * 256) + aiR[0];
            p1 = *(const f32x4*)(nb + 1 * 256) + aiR[1];
            p2 = *(const f32x4*)(nb + 2 * 256) + aiR[2];
            p3 = *(const f32x4*)(nb + 3 * 256) + aiR[3];
        }

#pragma unroll
        for (int nt = 0; nt < 4; nt++) {
            f16x8 bh0 = bHs[(0 * 4 + nt) * 64 + lane];
            f16x8 bl0 = bLs[(0 * 4 + nt) * 64 + lane];
            f16x8 bh1v = bHs[(1 * 4 + nt) * 64 + lane];
            f16x8 bl1 = bLs[(1 * 4 + nt) * 64 + lane];
            f32x4 acc = {bias4[nt], bias4[nt], bias4[nt], bias4[nt]};
            acc = __builtin_amdgcn_mfma_f32_16x16x32_f16(aH0, bh0, acc, 0, 0, 0);
            acc = __builtin_amdgcn_mfma_f32_16x16x32_f16(aH0, bl0, acc, 0, 0, 0);
            acc = __builtin_amdgcn_mfma_f32_16x16x32_f16(aH1, bh1v, acc, 0, 0, 0);
            acc = __builtin_amdgcn_mfma_f32_16x16x32_f16(aH1, bl1, acc, 0, 0, 0);
            f32x4 ev;
#pragma unroll
            for (int r4 = 0; r4 < 4; r4++) ev[r4] = __builtin_amdgcn_exp2f(acc[r4]);
            ev += 1.0f;
            f32x4 rv;
#pragma unroll
            for (int r4 = 0; r4 < 4; r4++) rv[r4] = __builtin_amdgcn_rcpf(ev[r4]);
            Vr4 += rv;
        }
    }

    red[t] = Vr4[0] + Vr4[1] + Vr4[2] + Vr4[3];
    __syncthreads();

    // waves 1-3 done: free their CU slots immediately
    if (wave != 0) return;

    // ---- wave-0-only: reduce + election + slim epilogue (no barriers) ----
    float r = red[t] + red[t + 64] + red[t + 128] + red[t + 192];
#pragma unroll
    for (int o = 32; o > 0; o >>= 1) r += __shfl_xor(r, o);
    float old = 0.f;
    if (t == 0) old = atomicAdd(Vpart + i, r);
    old = __shfl(old, 0);
    if (old == 0.0f) return;          // first arriver: partial stored, done
    float Rall = old + r;

    // diagonal (precomputed z), stage dgt/hrow in reused red[]
    {
        float z = diagz[i * L_DIM + t];
        float rr = __builtin_amdgcn_rcpf(__builtin_amdgcn_exp2f(z) + 1.0f);
        red[t] = fmaf(-2.0f, rr, 1.0f);                 // dgt
        red[64 + t] = LM[cat[i] * L_DIM + t];           // hrow
    }
    float S = be2[t];
#pragma unroll
    for (int m = 0; m < L_DIM; m++) S = fmaf(red[m], We2[m * L_DIM + t], S);
    float rd = __builtin_amdgcn_rcpf(__builtin_amdgcn_exp2f(S * CSCALE) + 1.0f);
#pragma unroll
    for (int o = 32; o > 0; o >>= 1) rd += __shfl_xor(rd, o);
    float V = fmaf(-2.0f, Rall - rd, (float)(1023 * L_DIM));
    float s = 0.f;
#pragma unroll
    for (int m = 0; m < L_DIM; m++) s = fmaf(red[64 + m], Wh1[m * L_DIM + t], s);
    s = fmaf(V, Wh1[L_DIM * L_DIM + t], s) + bh1[t];
    red[128 + t] = tanh_fast(s);                        // hh
    float s2 = 0.f;
#pragma unroll
    for (int m = 0; m < L_DIM; m++) s2 = fmaf(red[128 + m], Wh2[m * L_DIM + t], s2);
    float nh = tanh_fast(s2 + bh2[t]);
    float w = nh * Wo[t];
#pragma unroll
    for (int o = 32; o > 0; o >>= 1) w += __shfl_down(w, o);
    if (t == 0) atomicAdd(out, w + (i == 0 ? bo[0] : 0.f));
}

extern "C" void kernel_launch(void* const* d_in, const int* in_sizes, int n_in,
                              void* d_out, int out_size, void* d_ws, size_t ws_size,
                              hipStream_t stream) {
    const int*   cat = (const int*)  d_in[0];
    const float* Z   = (const float*)d_in[1];
    const float* LM  = (const float*)d_in[2];
    const float* We1 = (const float*)d_in[3];
    const float* be1 = (const float*)d_in[4];
    const float* We2 = (const float*)d_in[5];
    const float* be2 = (const float*)d_in[6];
    const float* Wh1 = (const float*)d_in[7];
    const float* bh1 = (const float*)d_in[8];
    const float* Wh2 = (const float*)d_in[9];
    const float* bh2 = (const float*)d_in[10];
    const float* Wo  = (const float*)d_in[11];
    const float* bo  = (const float*)d_in[12];
    float* out = (float*)d_out;

    float* ws    = (float*)d_ws;
    float* preI  = ws;                        // 1024*64 (c-prescaled)
    float* P3    = preI  + N_ATOMS * L_DIM;   // 1024*64 (packed, c-prescaled)
    float* diagz = P3    + N_ATOMS * L_DIM;   // 1024*64
    float* Vpart = diagz + N_ATOMS * L_DIM;   // 1024
    float* biasg = Vpart + N_ATOMS;           // 256
    f16x8* bHg   = (f16x8*)(biasg + 256);     // 8 KB
    f16x8* bLg   = bHg + 8 * 64;              // 8 KB
    // out is memset by the harness before each verify launch (R12/R13 established).

    k_prep<<<N_ATOMS / 4, 256, 0, stream>>>(cat, LM, We1, be1, We2, be2,
                                            preI, P3, diagz, Vpart, bHg, bLg, biasg);
    k_main<<<N_ATOMS * 2, 256, 0, stream>>>(cat, Z, LM, We1, preI, P3, diagz,
                                            bHg, bLg, biasg, We2, be2,
                                            Wh1, bh1, Wh2, bh2, Wo, bo,
                                            Vpart, out);
}